// Round 1
// baseline (648.827 us; speedup 1.0000x reference)
//
#include <hip/hip_runtime.h>
#include <hip/hip_bf16.h>
#include <stdint.h>

// Self-attention (no softmax) via matmul reassociation:
//   out = scale * (x Wt^T) [(x Wp^T)^T (x Wg^T)]   computed as
//   TP   = x @ [Wt;Wp]^T                  M=32768 N=512  K=1024   (bt)
//   Nmat = phi^T @ x         per batch    M=256   N=1024 K=4096   (tn)
//   MT   = scale * Wg @ Nmat^T  per batch M=1024  N=256  K=1024   (bt)
//   out  = theta @ MT^T      per batch    M=4096  N=1024 K=256    (bt, fp32 out)
// Total ~73 GFLOP (vs 447 GFLOP reference order), no 537MB att matrix.

typedef __attribute__((ext_vector_type(8))) short bf16x8;
typedef __attribute__((ext_vector_type(4))) float f32x4;

__device__ inline unsigned short f32_to_bf16_rne(float f) {
  union { float f; uint32_t u; } v; v.f = f;
  uint32_t r = v.u + 0x7fffu + ((v.u >> 16) & 1u);
  return (unsigned short)(r >> 16);
}

__device__ inline void gload_lds16(const void* g, void* lds) {
  __builtin_amdgcn_global_load_lds(
      (const __attribute__((address_space(1))) void*)g,
      (__attribute__((address_space(3))) void*)lds, 16, 0, 0);
}

// ---------------- fp32 -> bf16 convert, 4 el/thread ----------------
__global__ __launch_bounds__(256) void cvt_f32_bf16(
    const float* __restrict__ in, unsigned short* __restrict__ out, int n4) {
  int i = blockIdx.x * 256 + threadIdx.x;
  if (i >= n4) return;
  float4 v = ((const float4*)in)[i];
  ushort4 o;
  o.x = f32_to_bf16_rne(v.x);
  o.y = f32_to_bf16_rne(v.y);
  o.z = f32_to_bf16_rne(v.z);
  o.w = f32_to_bf16_rne(v.w);
  ((ushort4*)out)[i] = o;
}

// ---------------- C[M,N] = scale * A[M,K] @ B[N,K]^T (both K-contiguous) ----
// 128x128 tile, BK=32, 4 waves of 64x64 (4x4 frags of 16x16x32 bf16 MFMA).
// Staging via global_load_lds width-16 (m97 structure).
template <bool OUT_F32>
__global__ __launch_bounds__(256) void gemm_bt(
    const unsigned short* __restrict__ A, const unsigned short* __restrict__ B,
    void* __restrict__ Cv,
    int K, int lda, int ldb, int ldc,
    long long sA, long long sB, long long sC, float scale) {
  __shared__ unsigned short As[128 * 32];
  __shared__ unsigned short Bs[128 * 32];

  const int tid  = threadIdx.x;
  const int lane = tid & 63;
  const int wave = tid >> 6;
  const int m0 = blockIdx.y * 128;
  const int n0 = blockIdx.x * 128;
  const int z  = blockIdx.z;

  A += (long long)z * sA;
  B += (long long)z * sB;

  const int sub = lane >> 2;       // row within 16-row chunk
  const int kk  = (lane & 3) * 8;  // k element offset within BK
  const int wm = (wave >> 1) * 64;
  const int wn = (wave & 1) * 64;
  const int li = lane & 15;
  const int q  = lane >> 4;

  f32x4 acc[4][4] = {};

  for (int k0 = 0; k0 < K; k0 += 32) {
#pragma unroll
    for (int r = 0; r < 2; ++r) {
      int chunk = r * 4 + wave;          // wave-uniform LDS chunk
      int row = chunk * 16 + sub;
      gload_lds16(A + (long long)(m0 + row) * lda + k0 + kk, (char*)As + chunk * 1024);
      gload_lds16(B + (long long)(n0 + row) * ldb + k0 + kk, (char*)Bs + chunk * 1024);
    }
    __syncthreads();
    bf16x8 af[4], bfr[4];
#pragma unroll
    for (int i = 0; i < 4; ++i) {
      af[i]  = *(const bf16x8*)&As[(wm + i * 16 + li) * 32 + q * 8];
      bfr[i] = *(const bf16x8*)&Bs[(wn + i * 16 + li) * 32 + q * 8];
    }
#pragma unroll
    for (int i = 0; i < 4; ++i)
#pragma unroll
      for (int j = 0; j < 4; ++j)
        acc[i][j] = __builtin_amdgcn_mfma_f32_16x16x32_bf16(af[i], bfr[j], acc[i][j], 0, 0, 0);
    __syncthreads();
  }

  // epilogue: D row = q*4+r, col = lane&15 (verified C/D layout)
  if (OUT_F32) {
    float* C = (float*)Cv + (long long)z * sC;
#pragma unroll
    for (int i = 0; i < 4; ++i)
#pragma unroll
      for (int j = 0; j < 4; ++j)
#pragma unroll
        for (int r = 0; r < 4; ++r) {
          int row = m0 + wm + i * 16 + q * 4 + r;
          int col = n0 + wn + j * 16 + li;
          C[(long long)row * ldc + col] = acc[i][j][r] * scale;
        }
  } else {
    unsigned short* C = (unsigned short*)Cv + (long long)z * sC;
#pragma unroll
    for (int i = 0; i < 4; ++i)
#pragma unroll
      for (int j = 0; j < 4; ++j)
#pragma unroll
        for (int r = 0; r < 4; ++r) {
          int row = m0 + wm + i * 16 + q * 4 + r;
          int col = n0 + wn + j * 16 + li;
          C[(long long)row * ldc + col] = f32_to_bf16_rne(acc[i][j][r] * scale);
        }
  }
}

// ---------------- C[M,N] = A[K,M]^T @ B[K,N] (both operands K-major) -------
// LDS-transpose staging through VGPRs; padded LDS rows (BK+8) to spread banks
// and keep 16B-aligned rows for ds_read_b128 fragment loads.
__global__ __launch_bounds__(256) void gemm_tn(
    const unsigned short* __restrict__ A, const unsigned short* __restrict__ B,
    unsigned short* __restrict__ C,
    int K, int lda, int ldb, int ldc,
    long long sA, long long sB, long long sC) {
  constexpr int BKP = 40;  // 32 + 8 pad
  __shared__ unsigned short At[128 * BKP];
  __shared__ unsigned short Bt[128 * BKP];

  const int tid  = threadIdx.x;
  const int lane = tid & 63;
  const int wave = tid >> 6;
  const int m0 = blockIdx.y * 128;
  const int n0 = blockIdx.x * 128;
  const int z  = blockIdx.z;

  const unsigned short* Ab = A + (long long)z * sA;
  const unsigned short* Bb = B + (long long)z * sB;

  const int kr = tid >> 4;         // 0..15 (k row within slab)
  const int mm = (tid & 15) * 8;   // 0..120 (col chunk)
  const int wm = (wave >> 1) * 64;
  const int wn = (wave & 1) * 64;
  const int li = lane & 15;
  const int q  = lane >> 4;

  f32x4 acc[4][4] = {};

  for (int k0 = 0; k0 < K; k0 += 32) {
    const unsigned short* Ag = Ab + (long long)(k0 + kr) * lda + m0 + mm;
    const unsigned short* Bg = Bb + (long long)(k0 + kr) * ldb + n0 + mm;
    bf16x8 va0 = *(const bf16x8*)Ag;
    bf16x8 va1 = *(const bf16x8*)(Ag + 16 * (long long)lda);
    bf16x8 vb0 = *(const bf16x8*)Bg;
    bf16x8 vb1 = *(const bf16x8*)(Bg + 16 * (long long)ldb);
    __syncthreads();  // previous iter's frag reads done before we overwrite
#pragma unroll
    for (int j = 0; j < 8; ++j) {
      At[(mm + j) * BKP + kr]      = va0[j];
      At[(mm + j) * BKP + kr + 16] = va1[j];
      Bt[(mm + j) * BKP + kr]      = vb0[j];
      Bt[(mm + j) * BKP + kr + 16] = vb1[j];
    }
    __syncthreads();
    bf16x8 af[4], bfr[4];
#pragma unroll
    for (int i = 0; i < 4; ++i) {
      af[i]  = *(const bf16x8*)&At[(wm + i * 16 + li) * BKP + q * 8];
      bfr[i] = *(const bf16x8*)&Bt[(wn + i * 16 + li) * BKP + q * 8];
    }
#pragma unroll
    for (int i = 0; i < 4; ++i)
#pragma unroll
      for (int j = 0; j < 4; ++j)
        acc[i][j] = __builtin_amdgcn_mfma_f32_16x16x32_bf16(af[i], bfr[j], acc[i][j], 0, 0, 0);
  }

  unsigned short* Cb = C + (long long)z * sC;
#pragma unroll
  for (int i = 0; i < 4; ++i)
#pragma unroll
    for (int j = 0; j < 4; ++j)
#pragma unroll
      for (int r = 0; r < 4; ++r) {
        int row = m0 + wm + i * 16 + q * 4 + r;
        int col = n0 + wn + j * 16 + li;
        Cb[(long long)row * ldc + col] = f32_to_bf16_rne(acc[i][j][r]);
      }
}

// ---------------------------------------------------------------------------
extern "C" void kernel_launch(void* const* d_in, const int* in_sizes, int n_in,
                              void* d_out, int out_size, void* d_ws, size_t ws_size,
                              hipStream_t stream) {
  const float* x  = (const float*)d_in[0];   // [8,4096,1024]
  const float* Wt = (const float*)d_in[1];   // [256,1024]
  const float* Wp = (const float*)d_in[2];   // [256,1024]
  const float* Wg = (const float*)d_in[3];   // [1024,1024]
  float* out = (float*)d_out;                // [8,4096,1024] fp32

  // workspace layout (bytes), total 112,197,632
  char* ws = (char*)d_ws;
  unsigned short* x_bf = (unsigned short*)(ws);               // 67,108,864 B
  unsigned short* TP   = (unsigned short*)(ws + 67108864);    // 33,554,432 B  [32768,512] theta|phi
  unsigned short* Nmat = (unsigned short*)(ws + 100663296);   //  4,194,304 B  [8,256,1024]
  unsigned short* MT   = (unsigned short*)(ws + 104857600);   //  4,194,304 B  [8,1024,256]
  unsigned short* Wtp  = (unsigned short*)(ws + 109051904);   //  1,048,576 B  [512,1024]
  unsigned short* Wgb  = (unsigned short*)(ws + 110100480);   //  2,097,152 B  [1024,1024]

  // bf16 converts
  cvt_f32_bf16<<<dim3(33554432 / 4 / 256), 256, 0, stream>>>(x, x_bf, 33554432 / 4);
  cvt_f32_bf16<<<dim3(262144 / 4 / 256), 256, 0, stream>>>(Wt, Wtp, 262144 / 4);
  cvt_f32_bf16<<<dim3(262144 / 4 / 256), 256, 0, stream>>>(Wp, Wtp + 262144, 262144 / 4);
  cvt_f32_bf16<<<dim3(1048576 / 4 / 256), 256, 0, stream>>>(Wg, Wgb, 1048576 / 4);

  // TP = x @ [Wt;Wp]^T : M=32768 N=512 K=1024 (cols 0..255 = theta, 256..511 = phi)
  gemm_bt<false><<<dim3(4, 256, 1), 256, 0, stream>>>(
      x_bf, Wtp, TP, 1024, 1024, 1024, 512, 0LL, 0LL, 0LL, 1.0f);

  // Nmat[b] = phi[b]^T @ x[b] : M=256 N=1024 K=4096 (TN form)
  gemm_tn<<<dim3(8, 2, 8), 256, 0, stream>>>(
      TP + 256, x_bf, Nmat, 4096, 512, 1024, 1024,
      2097152LL /*4096*512*/, 4194304LL /*4096*1024*/, 262144LL /*256*1024*/);

  // MT[b] = scale * Wg @ Nmat[b]^T : M=1024 N=256 K=1024
  gemm_bt<false><<<dim3(2, 8, 8), 256, 0, stream>>>(
      Wgb, Nmat, MT, 1024, 1024, 1024, 256,
      0LL, 262144LL, 262144LL, 0.03125f /*1/sqrt(1024)*/);

  // out[b] = theta[b] @ MT[b]^T : M=4096 N=1024 K=256, fp32 out
  gemm_bt<true><<<dim3(8, 32, 8), 256, 0, stream>>>(
      TP, MT, out, 256, 512, 256, 1024,
      2097152LL /*4096*512*/, 262144LL /*1024*256*/, 4194304LL /*4096*1024*/, 1.0f);
}

// Round 2
// 482.778 us; speedup vs baseline: 1.3439x; 1.3439x over previous
//
#include <hip/hip_runtime.h>
#include <hip/hip_bf16.h>
#include <stdint.h>

// Self-attention (no softmax) via matmul reassociation — ALL gemms in proven
// m97-style "bt" form (both operands K-contiguous):
//   theta = x @ Wt^T                       [32768,256]           17.2 GF
//   phiT  = Wp @ x^T                       [256,32768] n-contig  17.2 GF
//   xT    = transpose(x) -> bf16           [8,1024,4096] n-contig
//   Rt    = phiT x xT   (= phi^T x)        [8,256,1024] K=4096   17.2 GF
//   MT    = scale * Wg x Rt (= Wg x^T phi) [8,1024,256]           4.3 GF
//   out   = theta x MT                     [8,4096,1024] fp32    17.2 GF
// Round-1 gemm_tn (300us, 2.2% MfmaUtil, 6.5e7 bank conflicts) eliminated.

typedef __attribute__((ext_vector_type(8))) short bf16x8;
typedef __attribute__((ext_vector_type(4))) float f32x4;

__device__ inline unsigned short f32_to_bf16_rne(float f) {
  union { float f; uint32_t u; } v; v.f = f;
  uint32_t r = v.u + 0x7fffu + ((v.u >> 16) & 1u);
  return (unsigned short)(r >> 16);
}

__device__ inline void gload_lds16(const void* g, void* lds) {
  __builtin_amdgcn_global_load_lds(
      (const __attribute__((address_space(1))) void*)g,
      (__attribute__((address_space(3))) void*)lds, 16, 0, 0);
}

// ---------------- fp32 -> bf16 convert, 4 el/thread ----------------
__global__ __launch_bounds__(256) void cvt_f32_bf16(
    const float* __restrict__ in, unsigned short* __restrict__ out, int n4) {
  int i = blockIdx.x * 256 + threadIdx.x;
  if (i >= n4) return;
  float4 v = ((const float4*)in)[i];
  ushort4 o;
  o.x = f32_to_bf16_rne(v.x);
  o.y = f32_to_bf16_rne(v.y);
  o.z = f32_to_bf16_rne(v.z);
  o.w = f32_to_bf16_rne(v.w);
  ((ushort4*)out)[i] = o;
}

// ---------------- x [8,4096,1024] fp32 -> xT [8,1024,4096] bf16 ------------
// 64n x 64f tile per block through LDS with xor-swizzle: element (f,n) lives
// at f*64 + (n ^ ((f>>3)&7)*8). Swizzle is a multiple of 8 so 8-n-contiguous
// runs stay contiguous & 16B-aligned (b128 reads); b16 stores land 2-way max.
__global__ __launch_bounds__(256) void transpose_cvt(
    const float* __restrict__ x, unsigned short* __restrict__ xT) {
  __shared__ unsigned short tile[64 * 64];
  const int tid = threadIdx.x;
  const int n0 = blockIdx.x * 64;
  const int f0 = blockIdx.y * 64;
  const long long b = blockIdx.z;
  const float* xb = x + b * 4096 * 1024;
  unsigned short* xTb = xT + b * 1024 * 4096;

  {  // phase 1: coalesced fp32 read, cvt, swizzled LDS store
    const int c4 = (tid & 15) * 4;  // f offset
    const int r  = tid >> 4;        // n row base
#pragma unroll
    for (int rr = 0; rr < 4; ++rr) {
      int n = rr * 16 + r;
      float4 v = *(const float4*)&xb[(long long)(n0 + n) * 1024 + f0 + c4];
      unsigned short e[4] = {f32_to_bf16_rne(v.x), f32_to_bf16_rne(v.y),
                             f32_to_bf16_rne(v.z), f32_to_bf16_rne(v.w)};
#pragma unroll
      for (int j = 0; j < 4; ++j) {
        int f = c4 + j;
        int s = ((f >> 3) & 7) * 8;
        tile[f * 64 + (n ^ s)] = e[j];
      }
    }
  }
  __syncthreads();
  {  // phase 2: b128 LDS read along n, coalesced 16B global store
    const int wave = tid >> 6, lane = tid & 63;
    const int nc = (lane & 7) * 8;
    const int fr = lane >> 3;
#pragma unroll
    for (int it = 0; it < 2; ++it) {
      int f = it * 32 + wave * 8 + fr;
      int s = ((f >> 3) & 7) * 8;
      bf16x8 v = *(const bf16x8*)&tile[f * 64 + (nc ^ s)];
      *(bf16x8*)&xTb[(long long)(f0 + f) * 4096 + n0 + nc] = v;
    }
  }
}

// ---------------- C[M,N] = scale * A[M,K] @ B[N,K]^T (both K-contiguous) ----
// 128x128 tile, BK=32, 4 waves of 64x64 (4x4 frags of 16x16x32 bf16 MFMA).
// Staging via global_load_lds width-16 (m97 structure).
template <bool OUT_F32>
__global__ __launch_bounds__(256) void gemm_bt(
    const unsigned short* __restrict__ A, const unsigned short* __restrict__ B,
    void* __restrict__ Cv,
    int K, int lda, int ldb, int ldc,
    long long sA, long long sB, long long sC, float scale) {
  __shared__ unsigned short As[128 * 32];
  __shared__ unsigned short Bs[128 * 32];

  const int tid  = threadIdx.x;
  const int lane = tid & 63;
  const int wave = tid >> 6;
  const int m0 = blockIdx.y * 128;
  const int n0 = blockIdx.x * 128;
  const int z  = blockIdx.z;

  A += (long long)z * sA;
  B += (long long)z * sB;

  const int sub = lane >> 2;       // row within 16-row chunk
  const int kk  = (lane & 3) * 8;  // k element offset within BK
  const int wm = (wave >> 1) * 64;
  const int wn = (wave & 1) * 64;
  const int li = lane & 15;
  const int q  = lane >> 4;

  f32x4 acc[4][4] = {};

  for (int k0 = 0; k0 < K; k0 += 32) {
#pragma unroll
    for (int r = 0; r < 2; ++r) {
      int chunk = r * 4 + wave;          // wave-uniform LDS chunk
      int row = chunk * 16 + sub;
      gload_lds16(A + (long long)(m0 + row) * lda + k0 + kk, (char*)As + chunk * 1024);
      gload_lds16(B + (long long)(n0 + row) * ldb + k0 + kk, (char*)Bs + chunk * 1024);
    }
    __syncthreads();
    bf16x8 af[4], bfr[4];
#pragma unroll
    for (int i = 0; i < 4; ++i) {
      af[i]  = *(const bf16x8*)&As[(wm + i * 16 + li) * 32 + q * 8];
      bfr[i] = *(const bf16x8*)&Bs[(wn + i * 16 + li) * 32 + q * 8];
    }
#pragma unroll
    for (int i = 0; i < 4; ++i)
#pragma unroll
      for (int j = 0; j < 4; ++j)
        acc[i][j] = __builtin_amdgcn_mfma_f32_16x16x32_bf16(af[i], bfr[j], acc[i][j], 0, 0, 0);
    __syncthreads();
  }

  // epilogue: D row = q*4+r, col = lane&15 (verified C/D layout)
  if (OUT_F32) {
    float* C = (float*)Cv + (long long)z * sC;
#pragma unroll
    for (int i = 0; i < 4; ++i)
#pragma unroll
      for (int j = 0; j < 4; ++j)
#pragma unroll
        for (int r = 0; r < 4; ++r) {
          int row = m0 + wm + i * 16 + q * 4 + r;
          int col = n0 + wn + j * 16 + li;
          C[(long long)row * ldc + col] = acc[i][j][r] * scale;
        }
  } else {
    unsigned short* C = (unsigned short*)Cv + (long long)z * sC;
#pragma unroll
    for (int i = 0; i < 4; ++i)
#pragma unroll
      for (int j = 0; j < 4; ++j)
#pragma unroll
        for (int r = 0; r < 4; ++r) {
          int row = m0 + wm + i * 16 + q * 4 + r;
          int col = n0 + wn + j * 16 + li;
          C[(long long)row * ldc + col] = f32_to_bf16_rne(acc[i][j][r] * scale);
        }
  }
}

// ---------------------------------------------------------------------------
extern "C" void kernel_launch(void* const* d_in, const int* in_sizes, int n_in,
                              void* d_out, int out_size, void* d_ws, size_t ws_size,
                              hipStream_t stream) {
  const float* x  = (const float*)d_in[0];   // [8,4096,1024]
  const float* Wt = (const float*)d_in[1];   // [256,1024]
  const float* Wp = (const float*)d_in[2];   // [256,1024]
  const float* Wg = (const float*)d_in[3];   // [1024,1024]
  float* out = (float*)d_out;                // [8,4096,1024] fp32

  // workspace layout (bytes), total 112,197,632 (same as round 1, proven fit)
  char* ws = (char*)d_ws;
  unsigned short* x_bf = (unsigned short*)(ws);               // 67,108,864  x bf16 [32768,1024]
  unsigned short* xT   = (unsigned short*)(ws);               // ALIASES x_bf: xT [8,1024,4096]
                                                              // (written after last x_bf read, stream-ordered)
  unsigned short* Th   = (unsigned short*)(ws + 67108864);    // 16,777,216  theta [32768,256]
  unsigned short* PhT  = (unsigned short*)(ws + 83886080);    // 16,777,216  phiT  [256,32768]
  unsigned short* Rt   = (unsigned short*)(ws + 100663296);   //  4,194,304  Rt [8,256,1024]
  unsigned short* MT   = (unsigned short*)(ws + 104857600);   //  4,194,304  MT [8,1024,256]
  unsigned short* Wtb  = (unsigned short*)(ws + 109051904);   //    524,288  Wt bf16
  unsigned short* Wpb  = (unsigned short*)(ws + 109576192);   //    524,288  Wp bf16
  unsigned short* Wgb  = (unsigned short*)(ws + 110100480);   //  2,097,152  Wg bf16

  // bf16 converts
  cvt_f32_bf16<<<dim3(33554432 / 4 / 256), 256, 0, stream>>>(x, x_bf, 33554432 / 4);
  cvt_f32_bf16<<<dim3(262144 / 4 / 256), 256, 0, stream>>>(Wt, Wtb, 262144 / 4);
  cvt_f32_bf16<<<dim3(262144 / 4 / 256), 256, 0, stream>>>(Wp, Wpb, 262144 / 4);
  cvt_f32_bf16<<<dim3(1048576 / 4 / 256), 256, 0, stream>>>(Wg, Wgb, 1048576 / 4);

  // theta = x @ Wt^T : M=32768 N=256 K=1024
  gemm_bt<false><<<dim3(2, 256, 1), 256, 0, stream>>>(
      x_bf, Wtb, Th, 1024, 1024, 1024, 256, 0LL, 0LL, 0LL, 1.0f);

  // phiT = Wp @ x^T : M=256 N=32768 K=1024  (n-contiguous phi)
  gemm_bt<false><<<dim3(256, 2, 1), 256, 0, stream>>>(
      Wpb, x_bf, PhT, 1024, 1024, 1024, 32768, 0LL, 0LL, 0LL, 1.0f);

  // xT = transpose(x) -> bf16 (reads pristine fp32 x; overwrites x_bf region)
  transpose_cvt<<<dim3(64, 16, 8), 256, 0, stream>>>(x, xT);

  // Rt[b] = phiT_b @ xT_b^T = phi^T x : M=256 N=1024 K=4096
  gemm_bt<false><<<dim3(8, 2, 8), 256, 0, stream>>>(
      PhT, xT, Rt, 4096, 32768, 4096, 1024,
      4096LL, 4194304LL, 262144LL, 1.0f);

  // MT[b] = scale * Wg @ Rt_b^T : M=1024 N=256 K=1024
  gemm_bt<false><<<dim3(2, 8, 8), 256, 0, stream>>>(
      Wgb, Rt, MT, 1024, 1024, 1024, 256,
      0LL, 262144LL, 262144LL, 0.03125f /*1/sqrt(1024)*/);

  // out[b] = theta_b @ MT_b^T : M=4096 N=1024 K=256, fp32 out
  gemm_bt<true><<<dim3(8, 32, 8), 256, 0, stream>>>(
      Th, MT, out, 256, 256, 256, 1024,
      1048576LL, 262144LL, 4194304LL, 1.0f);
}

// Round 3
// 436.785 us; speedup vs baseline: 1.4855x; 1.1053x over previous
//
#include <hip/hip_runtime.h>
#include <hip/hip_bf16.h>
#include <stdint.h>

// Self-attention (no softmax) via matmul reassociation — all gemms m97-style
// "bt" (both operands K-contiguous), small-grid gemms split-K'd:
//   theta = x @ Wt^T                      [32768,256]   512 blk
//   phiT  = Wp @ x^T (via x_bf k-contig)  [256,32768]   512 blk
//   xT    = transpose(x) bf16 (in d_out)  [8,1024,4096]
//   Rt    = phiT x xT  (= phi^T x)        [8,256,1024]  K=4096 split-4, 512 blk
//   MT    = scale*Wg x Rt                 [8,1024,256]  K=1024 split-2, 256 blk
//   out   = theta x MT                    [8,4096,1024] fp32, 2048 blk
// d_out doubles as scratch (xT + fp32 split partials) before the final gemm
// fully overwrites it.

typedef __attribute__((ext_vector_type(8))) short bf16x8;
typedef __attribute__((ext_vector_type(4))) float f32x4;

__device__ inline unsigned short f32_to_bf16_rne(float f) {
  union { float f; uint32_t u; } v; v.f = f;
  uint32_t r = v.u + 0x7fffu + ((v.u >> 16) & 1u);
  return (unsigned short)(r >> 16);
}

__device__ inline void gload_lds16(const void* g, void* lds) {
  __builtin_amdgcn_global_load_lds(
      (const __attribute__((address_space(1))) void*)g,
      (__attribute__((address_space(3))) void*)lds, 16, 0, 0);
}

// ---------------- all three weights fp32->bf16 in one dispatch -------------
__global__ __launch_bounds__(256) void cvt_weights(
    const float* __restrict__ Wt, const float* __restrict__ Wp,
    const float* __restrict__ Wg, unsigned short* __restrict__ Wtb,
    unsigned short* __restrict__ Wpb, unsigned short* __restrict__ Wgb) {
  int i = blockIdx.x * 256 + threadIdx.x;  // float4 index, total 393216
  const float* src;
  unsigned short* dst;
  int off;
  if (i < 65536) { src = Wt; dst = Wtb; off = i; }
  else if (i < 131072) { src = Wp; dst = Wpb; off = i - 65536; }
  else { src = Wg; dst = Wgb; off = i - 131072; }
  float4 v = ((const float4*)src)[off];
  ushort4 o;
  o.x = f32_to_bf16_rne(v.x);
  o.y = f32_to_bf16_rne(v.y);
  o.z = f32_to_bf16_rne(v.z);
  o.w = f32_to_bf16_rne(v.w);
  ((ushort4*)dst)[off] = o;
}

// ------- fused: x fp32 -> x_bf (same layout) AND xT (transposed) bf16 ------
// 64n x 64f tile through LDS, xor-swizzle (n ^ ((f>>3)&7)*8): 8-contiguous
// n-runs stay 16B-aligned for b128 reads, b16 stores spread across banks.
__global__ __launch_bounds__(256) void xcvt_fused(
    const float* __restrict__ x, unsigned short* __restrict__ x_bf,
    unsigned short* __restrict__ xT) {
  __shared__ unsigned short tile[64 * 64];
  const int tid = threadIdx.x;
  const int n0 = blockIdx.x * 64;
  const int f0 = blockIdx.y * 64;
  const long long b = blockIdx.z;
  const float* xb = x + b * 4194304LL;
  unsigned short* xbf = x_bf + b * 4194304LL;
  unsigned short* xTb = xT + b * 4194304LL;

  {  // phase 1: coalesced fp32 read, cvt, write x_bf + swizzled LDS store
    const int c4 = (tid & 15) * 4;
    const int r  = tid >> 4;
#pragma unroll
    for (int rr = 0; rr < 4; ++rr) {
      int n = rr * 16 + r;
      float4 v = *(const float4*)&xb[(long long)(n0 + n) * 1024 + f0 + c4];
      unsigned short e[4] = {f32_to_bf16_rne(v.x), f32_to_bf16_rne(v.y),
                             f32_to_bf16_rne(v.z), f32_to_bf16_rne(v.w)};
      ushort4 o; o.x = e[0]; o.y = e[1]; o.z = e[2]; o.w = e[3];
      *(ushort4*)&xbf[(long long)(n0 + n) * 1024 + f0 + c4] = o;
#pragma unroll
      for (int j = 0; j < 4; ++j) {
        int f = c4 + j;
        int s = ((f >> 3) & 7) * 8;
        tile[f * 64 + (n ^ s)] = e[j];
      }
    }
  }
  __syncthreads();
  {  // phase 2: b128 LDS read along n, coalesced 16B global store to xT
    const int wave = tid >> 6, lane = tid & 63;
    const int nc = (lane & 7) * 8;
    const int fr = lane >> 3;
#pragma unroll
    for (int it = 0; it < 2; ++it) {
      int f = it * 32 + wave * 8 + fr;
      int s = ((f >> 3) & 7) * 8;
      bf16x8 v = *(const bf16x8*)&tile[f * 64 + (nc ^ s)];
      *(bf16x8*)&xTb[(long long)(f0 + f) * 4096 + n0 + nc] = v;
    }
  }
}

// ---------------- C[M,N] = scale * A[M,K] @ B[N,K]^T (both K-contiguous) ----
template <bool OUT_F32>
__global__ __launch_bounds__(256) void gemm_bt(
    const unsigned short* __restrict__ A, const unsigned short* __restrict__ B,
    void* __restrict__ Cv,
    int K, int lda, int ldb, int ldc,
    long long sA, long long sB, long long sC, float scale) {
  __shared__ unsigned short As[128 * 32];
  __shared__ unsigned short Bs[128 * 32];

  const int tid  = threadIdx.x;
  const int lane = tid & 63;
  const int wave = tid >> 6;
  const int m0 = blockIdx.y * 128;
  const int n0 = blockIdx.x * 128;
  const int z  = blockIdx.z;

  A += (long long)z * sA;
  B += (long long)z * sB;

  const int sub = lane >> 2;
  const int kk  = (lane & 3) * 8;
  const int wm = (wave >> 1) * 64;
  const int wn = (wave & 1) * 64;
  const int li = lane & 15;
  const int q  = lane >> 4;

  f32x4 acc[4][4] = {};

  for (int k0 = 0; k0 < K; k0 += 32) {
#pragma unroll
    for (int r = 0; r < 2; ++r) {
      int chunk = r * 4 + wave;
      int row = chunk * 16 + sub;
      gload_lds16(A + (long long)(m0 + row) * lda + k0 + kk, (char*)As + chunk * 1024);
      gload_lds16(B + (long long)(n0 + row) * ldb + k0 + kk, (char*)Bs + chunk * 1024);
    }
    __syncthreads();
    bf16x8 af[4], bfr[4];
#pragma unroll
    for (int i = 0; i < 4; ++i) {
      af[i]  = *(const bf16x8*)&As[(wm + i * 16 + li) * 32 + q * 8];
      bfr[i] = *(const bf16x8*)&Bs[(wn + i * 16 + li) * 32 + q * 8];
    }
#pragma unroll
    for (int i = 0; i < 4; ++i)
#pragma unroll
      for (int j = 0; j < 4; ++j)
        acc[i][j] = __builtin_amdgcn_mfma_f32_16x16x32_bf16(af[i], bfr[j], acc[i][j], 0, 0, 0);
    __syncthreads();
  }

  if (OUT_F32) {
    float* C = (float*)Cv + (long long)z * sC;
#pragma unroll
    for (int i = 0; i < 4; ++i)
#pragma unroll
      for (int j = 0; j < 4; ++j)
#pragma unroll
        for (int r = 0; r < 4; ++r) {
          int row = m0 + wm + i * 16 + q * 4 + r;
          int col = n0 + wn + j * 16 + li;
          C[(long long)row * ldc + col] = acc[i][j][r] * scale;
        }
  } else {
    unsigned short* C = (unsigned short*)Cv + (long long)z * sC;
#pragma unroll
    for (int i = 0; i < 4; ++i)
#pragma unroll
      for (int j = 0; j < 4; ++j)
#pragma unroll
        for (int r = 0; r < 4; ++r) {
          int row = m0 + wm + i * 16 + q * 4 + r;
          int col = n0 + wn + j * 16 + li;
          C[(long long)row * ldc + col] = f32_to_bf16_rne(acc[i][j][r] * scale);
        }
  }
}

// ------------- split-K variant: fp32 partials, z = batch*nsplit + split -----
__global__ __launch_bounds__(256) void gemm_bt_split(
    const unsigned short* __restrict__ A, const unsigned short* __restrict__ B,
    float* __restrict__ Cp,
    int Ks, int lda, int ldb, int ldc,
    long long sA, long long sB, long long sC, int nsplit) {
  __shared__ unsigned short As[128 * 32];
  __shared__ unsigned short Bs[128 * 32];

  const int tid  = threadIdx.x;
  const int lane = tid & 63;
  const int wave = tid >> 6;
  const int m0 = blockIdx.y * 128;
  const int n0 = blockIdx.x * 128;
  const int z  = blockIdx.z;
  const int batch = z / nsplit;
  const int split = z - batch * nsplit;

  A += batch * sA + (long long)split * Ks;   // k-contiguous: split offsets along k
  B += batch * sB + (long long)split * Ks;
  Cp += (long long)z * sC;

  const int sub = lane >> 2;
  const int kk  = (lane & 3) * 8;
  const int wm = (wave >> 1) * 64;
  const int wn = (wave & 1) * 64;
  const int li = lane & 15;
  const int q  = lane >> 4;

  f32x4 acc[4][4] = {};

  for (int k0 = 0; k0 < Ks; k0 += 32) {
#pragma unroll
    for (int r = 0; r < 2; ++r) {
      int chunk = r * 4 + wave;
      int row = chunk * 16 + sub;
      gload_lds16(A + (long long)(m0 + row) * lda + k0 + kk, (char*)As + chunk * 1024);
      gload_lds16(B + (long long)(n0 + row) * ldb + k0 + kk, (char*)Bs + chunk * 1024);
    }
    __syncthreads();
    bf16x8 af[4], bfr[4];
#pragma unroll
    for (int i = 0; i < 4; ++i) {
      af[i]  = *(const bf16x8*)&As[(wm + i * 16 + li) * 32 + q * 8];
      bfr[i] = *(const bf16x8*)&Bs[(wn + i * 16 + li) * 32 + q * 8];
    }
#pragma unroll
    for (int i = 0; i < 4; ++i)
#pragma unroll
      for (int j = 0; j < 4; ++j)
        acc[i][j] = __builtin_amdgcn_mfma_f32_16x16x32_bf16(af[i], bfr[j], acc[i][j], 0, 0, 0);
    __syncthreads();
  }

#pragma unroll
  for (int i = 0; i < 4; ++i)
#pragma unroll
    for (int j = 0; j < 4; ++j)
#pragma unroll
      for (int r = 0; r < 4; ++r) {
        int row = m0 + wm + i * 16 + q * 4 + r;
        int col = n0 + wn + j * 16 + li;
        Cp[(long long)row * ldc + col] = acc[i][j][r];
      }
}

// ---- sum nsplit fp32 slices (each 262144 els per batch-slice) -> bf16 -----
__global__ __launch_bounds__(256) void reduce_splits(
    const float* __restrict__ P, unsigned short* __restrict__ O,
    int nsplit, float scale) {
  int i = (blockIdx.x * 256 + threadIdx.x) * 4;
  int batch = i >> 18;          // / 262144
  int j = i & 262143;
  const float* p = P + (long long)batch * nsplit * 262144 + j;
  float4 s = *(const float4*)p;
  for (int t = 1; t < nsplit; ++t) {
    float4 v = *(const float4*)(p + (long long)t * 262144);
    s.x += v.x; s.y += v.y; s.z += v.z; s.w += v.w;
  }
  ushort4 o;
  o.x = f32_to_bf16_rne(s.x * scale);
  o.y = f32_to_bf16_rne(s.y * scale);
  o.z = f32_to_bf16_rne(s.z * scale);
  o.w = f32_to_bf16_rne(s.w * scale);
  ((ushort4*)O)[i >> 2] = o;
}

// ---------------------------------------------------------------------------
extern "C" void kernel_launch(void* const* d_in, const int* in_sizes, int n_in,
                              void* d_out, int out_size, void* d_ws, size_t ws_size,
                              hipStream_t stream) {
  const float* x  = (const float*)d_in[0];   // [8,4096,1024]
  const float* Wt = (const float*)d_in[1];   // [256,1024]
  const float* Wp = (const float*)d_in[2];   // [256,1024]
  const float* Wg = (const float*)d_in[3];   // [1024,1024]
  float* out = (float*)d_out;                // [8,4096,1024] fp32 (134 MB)

  // ws layout (<= 112,197,632 B proven):
  char* ws = (char*)d_ws;
  unsigned short* x_bf = (unsigned short*)(ws);               // 64 MB [32768,1024]
  unsigned short* Th   = (unsigned short*)(ws + 67108864);    // 16 MB theta [32768,256]
  unsigned short* PhT  = (unsigned short*)(ws + 83886080);    // 16 MB phiT [256,32768]
  unsigned short* Rt   = (unsigned short*)(ws + 100663296);   //  4 MB [8,256,1024]
  unsigned short* MT   = (unsigned short*)(ws + 104857600);   //  4 MB [8,1024,256]
  unsigned short* Wtb  = (unsigned short*)(ws + 109051904);
  unsigned short* Wpb  = (unsigned short*)(ws + 109576192);
  unsigned short* Wgb  = (unsigned short*)(ws + 110100480);

  // d_out as scratch until final gemm overwrites it:
  unsigned short* xT   = (unsigned short*)d_out;                      // 64 MB [8,1024,4096]
  float* RtP = (float*)((char*)d_out + 67108864);                     // 32 MB: 4 splits x 8 MB
  float* MTP = (float*)((char*)d_out + 100663296);                    // 16 MB: 2 splits x 8 MB

  cvt_weights<<<dim3(1536), 256, 0, stream>>>(Wt, Wp, Wg, Wtb, Wpb, Wgb);
  xcvt_fused<<<dim3(64, 16, 8), 256, 0, stream>>>(x, x_bf, xT);

  // theta = x @ Wt^T : M=32768 N=256 K=1024
  gemm_bt<false><<<dim3(2, 256, 1), 256, 0, stream>>>(
      x_bf, Wtb, Th, 1024, 1024, 1024, 256, 0LL, 0LL, 0LL, 1.0f);

  // phiT = Wp @ x^T : M=256 N=32768 K=1024
  gemm_bt<false><<<dim3(256, 2, 1), 256, 0, stream>>>(
      Wpb, x_bf, PhT, 1024, 1024, 1024, 32768, 0LL, 0LL, 0LL, 1.0f);

  // Rt[b] = phiT_b @ xT_b^T : M=256 N=1024 K=4096, split-4 (Ks=1024), 512 blk
  gemm_bt_split<<<dim3(8, 2, 32), 256, 0, stream>>>(
      PhT, xT, RtP, 1024, 32768, 4096, 1024,
      4096LL, 4194304LL, 262144LL, 4);
  reduce_splits<<<dim3(2048), 256, 0, stream>>>(RtP, Rt, 4, 1.0f);

  // MT[b] = scale * Wg @ Rt_b^T : M=1024 N=256 K=1024, split-2 (Ks=512), 256 blk
  gemm_bt_split<<<dim3(2, 8, 16), 256, 0, stream>>>(
      Wgb, Rt, MTP, 512, 1024, 1024, 256,
      0LL, 262144LL, 262144LL, 2);
  reduce_splits<<<dim3(2048), 256, 0, stream>>>(MTP, MT, 2, 0.03125f);

  // out[b] = theta_b @ MT_b^T : M=4096 N=1024 K=256, fp32 out
  gemm_bt<true><<<dim3(8, 32, 8), 256, 0, stream>>>(
      Th, MT, out, 256, 256, 256, 1024,
      1048576LL, 262144LL, 4194304LL, 1.0f);
}